// Round 6
// baseline (804.991 us; speedup 1.0000x reference)
//
#include <hip/hip_runtime.h>
#include <math.h>

#define NN 8
#define CC 256
#define HH 112
#define WW 112
#define MIP 8
#define EPS 1e-5f
#define NBLK 1792            // 7 blocks/CU on 256 CUs (capacity 8 -> 1 block slack)
#define NPLANE 2048          // NN*CC planes for phases 1 and 3
#define NPOS (NN * HH)       // 896 positions per branch; 2*NPOS == NBLK exactly

typedef float nvec4 __attribute__((ext_vector_type(4)));

// Self-resetting grid barrier state (load-time zero init; sense-reversing
// protocol leaves cnt==0 after each use, gen monotonically increases across
// graph replays -> no per-launch reset needed).
__device__ int g_cnt = 0;
__device__ int g_gen = 0;

__device__ __forceinline__ void grid_barrier() {
    __syncthreads();
    if (threadIdx.x == 0) {
        __threadfence();   // release: all prior global writes visible device-wide
        const int my_gen = __hip_atomic_load(&g_gen, __ATOMIC_ACQUIRE,
                                             __HIP_MEMORY_SCOPE_AGENT);
        const int prev = __hip_atomic_fetch_add(&g_cnt, 1, __ATOMIC_ACQ_REL,
                                                __HIP_MEMORY_SCOPE_AGENT);
        if (prev == NBLK - 1) {
            __hip_atomic_store(&g_cnt, 0, __ATOMIC_RELAXED,
                               __HIP_MEMORY_SCOPE_AGENT);
            __hip_atomic_fetch_add(&g_gen, 1, __ATOMIC_RELEASE,
                                   __HIP_MEMORY_SCOPE_AGENT);
        } else {
            int spins = 0;
            while (__hip_atomic_load(&g_gen, __ATOMIC_ACQUIRE,
                                     __HIP_MEMORY_SCOPE_AGENT) == my_gen) {
                __builtin_amdgcn_s_sleep(2);
                if (++spins > (1 << 22)) break;   // safety valve: no hangs
            }
        }
        __threadfence();   // acquire: other blocks' writes visible to us
    }
    __syncthreads();
}

// Pooled/attention buffer layout (position-major, channel-contiguous):
//   branch 0 (h-pool): P[((n*HH + h)*CC + c)]
//   branch 1 (w-pool): P[NN*HH*CC + ((n*WW + w)*CC + c)]
__global__ __launch_bounds__(256, 7) void fused_kernel(
    const float* __restrict__ x,
    const float* __restrict__ bn1_g, const float* __restrict__ bn1_b,
    const float* __restrict__ bn1_m, const float* __restrict__ bn1_v,
    const float* __restrict__ bn2_g, const float* __restrict__ bn2_b,
    const float* __restrict__ bn2_m, const float* __restrict__ bn2_v,
    const float* __restrict__ ds_w, const float* __restrict__ ds_b,
    const float* __restrict__ us_w, const float* __restrict__ us_b,
    float* __restrict__ pool, float* __restrict__ out) {
    const int t = threadIdx.x;

    __shared__ union {
        struct { float rowpart[HH][29]; float4 colpart[8][28]; } p1;  // 16.2 KB
        struct { float s[CC]; float dsh[MIP]; } p2;
        struct { float ah[HH]; float aw[WW]; } p3;
    } sm;

    // ------------------------- Phase 1: dual-axis pooling -------------------
#pragma unroll 1
    for (int b = blockIdx.x; b < NPLANE; b += NBLK) {   // plane = n*CC + c
        const int n = b / CC;
        const int c = b % CC;
        const nvec4* p4 = (const nvec4*)(x + (size_t)b * (HH * WW));

        if (t < 224) {
            const int g = t / 28;                  // row group 0..7
            const int j = t % 28;                  // float4 column 0..27
            float4 ca = make_float4(0.f, 0.f, 0.f, 0.f);
#pragma unroll
            for (int k = 0; k < 14; ++k) {
                const int r = g + 8 * k;
                nvec4 v = __builtin_nontemporal_load(&p4[r * 28 + j]);
                ca.x += v.x; ca.y += v.y; ca.z += v.z; ca.w += v.w;
                sm.p1.rowpart[r][j] = v.x + v.y + v.z + v.w;
            }
            sm.p1.colpart[g][j] = ca;
        }
        __syncthreads();

        if (t < HH) {
            float s = 0.f;
#pragma unroll
            for (int j = 0; j < 28; ++j) s += sm.p1.rowpart[t][j];
            pool[((size_t)(n * HH + t)) * CC + c] = s * (1.0f / WW);
        } else if (t < 112 + WW) {
            const int w = t - 112;
            const float* cp = (const float*)&sm.p1.colpart[0][0];  // [8][112]
            float s = 0.f;
#pragma unroll
            for (int g = 0; g < 8; ++g) s += cp[g * 112 + w];
            pool[(size_t)(NN * HH * CC) + ((size_t)(n * WW + w)) * CC + c] =
                s * (1.0f / HH);
        }
        __syncthreads();   // LDS reuse fence before next plane
    }
    grid_barrier();

    // --------------- Phase 2: BN -> C->MIP relu -> MIP->C sigmoid ----------
    // NBLK == 2*NPOS: exactly one item per block, no idle blocks.
    {
        const int item = blockIdx.x;
        const int branch = item >= NPOS;
        const int pos = item - branch * NPOS;
        const int c = t;

        const float* g  = branch ? bn2_g : bn1_g;
        const float* be = branch ? bn2_b : bn1_b;
        const float* mn = branch ? bn2_m : bn1_m;
        const float* vr = branch ? bn2_v : bn1_v;

        const size_t idx =
            (size_t)branch * (NN * HH * CC) + (size_t)pos * CC + c;

        const float v = pool[idx];
        const float scale = g[c] * rsqrtf(vr[c] + EPS);
        const float vb = v * scale + (be[c] - mn[c] * scale);
        sm.p2.s[c] = vb;
        __syncthreads();

        {
            const int grp = c >> 5;
            const int l = c & 31;
            float partial = 0.f;
#pragma unroll
            for (int k = 0; k < CC / 32; ++k) {
                const int cc = l + k * 32;
                partial += ds_w[grp * CC + cc] * sm.p2.s[cc];
            }
#pragma unroll
            for (int off = 16; off > 0; off >>= 1)
                partial += __shfl_down(partial, off, 32);
            if (l == 0) sm.p2.dsh[grp] = fmaxf(partial + ds_b[grp], 0.f);
        }
        __syncthreads();

        float acc = us_b[c];
#pragma unroll
        for (int m = 0; m < MIP; ++m) acc += us_w[c * MIP + m] * sm.p2.dsh[m];
        pool[idx] = 1.0f / (1.0f + expf(-acc));
    }
    grid_barrier();

    // ------------------------- Phase 3: apply + h-swish ---------------------
#pragma unroll 1
    for (int b = blockIdx.x; b < NPLANE; b += NBLK) {   // plane = n*CC + c
        const int n = b / CC;
        const int c = b % CC;

        if (t < HH) {
            sm.p3.ah[t] = pool[((size_t)(n * HH + t)) * CC + c];
        } else if (t >= 128 && t < 128 + WW) {
            const int w = t - 128;
            sm.p3.aw[w] =
                pool[(size_t)(NN * HH * CC) + ((size_t)(n * WW + w)) * CC + c];
        }
        __syncthreads();

        const nvec4* xp = (const nvec4*)(x + (size_t)b * (HH * WW));
        nvec4* op = (nvec4*)(out + (size_t)b * (HH * WW));
#pragma unroll 4
        for (int i = t; i < HH * (WW / 4); i += 256) {
            const int h = i / (WW / 4);
            const int w4 = i % (WW / 4);
            nvec4 xv = __builtin_nontemporal_load(&xp[i]);
            const float a_h = sm.p3.ah[h];
            nvec4 o;
            o.x = xv.x * (sm.p3.aw[w4 * 4 + 0] * a_h) + xv.x;
            o.y = xv.y * (sm.p3.aw[w4 * 4 + 1] * a_h) + xv.y;
            o.z = xv.z * (sm.p3.aw[w4 * 4 + 2] * a_h) + xv.z;
            o.w = xv.w * (sm.p3.aw[w4 * 4 + 3] * a_h) + xv.w;
            nvec4 r;
            r.x = o.x * fminf(fmaxf(o.x + 3.0f, 0.0f), 6.0f) * (1.0f / 6.0f);
            r.y = o.y * fminf(fmaxf(o.y + 3.0f, 0.0f), 6.0f) * (1.0f / 6.0f);
            r.z = o.z * fminf(fmaxf(o.z + 3.0f, 0.0f), 6.0f) * (1.0f / 6.0f);
            r.w = o.w * fminf(fmaxf(o.w + 3.0f, 0.0f), 6.0f) * (1.0f / 6.0f);
            __builtin_nontemporal_store(r, &op[i]);
        }
        __syncthreads();   // LDS reuse fence before next plane
    }
}

extern "C" void kernel_launch(void* const* d_in, const int* in_sizes, int n_in,
                              void* d_out, int out_size, void* d_ws, size_t ws_size,
                              hipStream_t stream) {
    const float* x     = (const float*)d_in[0];
    const float* bn1_g = (const float*)d_in[1];
    const float* bn1_b = (const float*)d_in[2];
    const float* bn1_m = (const float*)d_in[3];
    const float* bn1_v = (const float*)d_in[4];
    const float* bn2_g = (const float*)d_in[5];
    const float* bn2_b = (const float*)d_in[6];
    const float* bn2_m = (const float*)d_in[7];
    const float* bn2_v = (const float*)d_in[8];
    const float* ds_w  = (const float*)d_in[9];
    const float* ds_b  = (const float*)d_in[10];
    const float* us_w  = (const float*)d_in[11];
    const float* us_b  = (const float*)d_in[12];
    float* out  = (float*)d_out;
    float* pool = (float*)d_ws;   // 2*N*112*C*4 = 1.75 MB

    fused_kernel<<<NBLK, 256, 0, stream>>>(x,
        bn1_g, bn1_b, bn1_m, bn1_v, bn2_g, bn2_b, bn2_m, bn2_v,
        ds_w, ds_b, us_w, us_b, pool, out);
}

// Round 7
// 263.806 us; speedup vs baseline: 3.0515x; 3.0515x over previous
//
#include <hip/hip_runtime.h>
#include <math.h>

#define NN 8
#define CC 256
#define HH 112
#define WW 112
#define MIP 8
#define EPS 1e-5f
#define NPOS 224                  // 112 h-positions + 112 w-positions per n
#define WOFF (NN * HH * CC)       // w-branch offset in pool buffer

typedef float nvec4 __attribute__((ext_vector_type(4)));

// ---------------------------------------------------------------------------
// K1: dual-axis average pooling with BN folded in (BN is per-channel affine,
// commutes with the mean). One block per (n,c) plane, NT loads (read-once).
// pool layout: h-branch P[(n*HH+h)*CC+c] (bn1 applied);
//              w-branch P[WOFF+(n*WW+w)*CC+c] (bn2 applied).
// ---------------------------------------------------------------------------
__global__ __launch_bounds__(256) void pool_bn_kernel(
    const float* __restrict__ x,
    const float* __restrict__ bn1_g, const float* __restrict__ bn1_b,
    const float* __restrict__ bn1_m, const float* __restrict__ bn1_v,
    const float* __restrict__ bn2_g, const float* __restrict__ bn2_b,
    const float* __restrict__ bn2_m, const float* __restrict__ bn2_v,
    float* __restrict__ pool) {
    __shared__ float rowpart[HH][29];
    __shared__ float4 colpart[8][28];
    const int b = blockIdx.x;                // n*CC + c
    const int n = b / CC;
    const int c = b % CC;
    const int t = threadIdx.x;

    const nvec4* p4 = (const nvec4*)(x + (size_t)b * (HH * WW));

    if (t < 224) {
        const int g = t / 28;                // row group 0..7
        const int j = t % 28;                // float4 column 0..27
        float4 ca = make_float4(0.f, 0.f, 0.f, 0.f);
#pragma unroll
        for (int k = 0; k < 14; ++k) {
            const int r = g + 8 * k;
            nvec4 v = __builtin_nontemporal_load(&p4[r * 28 + j]);
            ca.x += v.x; ca.y += v.y; ca.z += v.z; ca.w += v.w;
            rowpart[r][j] = v.x + v.y + v.z + v.w;
        }
        colpart[g][j] = ca;
    }
    __syncthreads();

    if (t < HH) {
        // row mean (over w) -> h-branch, bn1 folded
        float s = 0.f;
#pragma unroll
        for (int j = 0; j < 28; ++j) s += rowpart[t][j];
        const float sc = bn1_g[c] * rsqrtf(bn1_v[c] + EPS);
        const float sh = bn1_b[c] - bn1_m[c] * sc;
        pool[((size_t)(n * HH + t)) * CC + c] = (s * (1.0f / WW)) * sc + sh;
    } else if (t < 112 + WW) {
        // column mean (over h) -> w-branch, bn2 folded
        const int w = t - 112;
        const float* cp = (const float*)&colpart[0][0];   // [8][112] floats
        float s = 0.f;
#pragma unroll
        for (int g = 0; g < 8; ++g) s += cp[g * 112 + w];
        const float sc = bn2_g[c] * rsqrtf(bn2_v[c] + EPS);
        const float sh = bn2_b[c] - bn2_m[c] * sc;
        pool[(size_t)WOFF + ((size_t)(n * WW + w)) * CC + c] =
            (s * (1.0f / HH)) * sc + sh;
    }
}

// ---------------------------------------------------------------------------
// K2: att (redundant per block) + apply, no grid barrier.
// 1024 blocks = (n, channel-pair): n = b>>7, c0 = (b&127)*2.
// Phase A: 4 waves x 56 positions; lane owns 4 channels; ds_w preloaded to
//   registers; select-based reduce-scatter -> lane holds dot for m=l&7;
//   us+sigmoid -> aL in LDS. Pool rows are L2-resident (1.79 MB buffer).
// Phase B: proven streaming apply + h-swish for planes c0, c0+1 (x is
//   L3-resident after K1).
// ---------------------------------------------------------------------------
__global__ __launch_bounds__(256) void att_apply_kernel(
    const float* __restrict__ x,
    const float* __restrict__ ds_w, const float* __restrict__ ds_b,
    const float* __restrict__ us_w, const float* __restrict__ us_b,
    const float* __restrict__ pool, float* __restrict__ out) {
    __shared__ float aL[2][NPOS];

    const int b = blockIdx.x;
    const int n = b >> 7;
    const int c0 = (b & 127) << 1;
    const int t = threadIdx.x;
    const int l = t & 63;
    const int wave = t >> 6;
    const int m = l & 7;

    // Loop-invariant preloads: lane l holds ds_w[m][4l..4l+3] for all m.
    const nvec4* dsw4 = (const nvec4*)ds_w;
    nvec4 w4[8];
#pragma unroll
    for (int mm = 0; mm < 8; ++mm) w4[mm] = dsw4[mm * 64 + l];
    const float dsb  = ds_b[m];
    const float usw0 = us_w[c0 * MIP + m];
    const float usw1 = us_w[(c0 + 1) * MIP + m];
    const float usb0 = us_b[c0];
    const float usb1 = us_b[c0 + 1];

    const float* poolH = pool + (size_t)(n * HH) * CC;
    const float* poolW = pool + WOFF + (size_t)(n * WW) * CC;

    const bool b0 = (l & 1) != 0, b1 = (l & 2) != 0, b2 = (l & 4) != 0;

#pragma unroll 1
    for (int i = 0; i < 56; ++i) {
        const int p = wave * 56 + i;
        const float* row = (p < HH) ? (poolH + (size_t)p * CC)
                                    : (poolW + (size_t)(p - HH) * CC);
        nvec4 v = ((const nvec4*)row)[l];      // coalesced: wave reads full row
        float r[8];
#pragma unroll
        for (int mm = 0; mm < 8; ++mm)
            r[mm] = v.x * w4[mm].x + v.y * w4[mm].y +
                    v.z * w4[mm].z + v.w * w4[mm].w;

        // Reduce-scatter within octet: lane ends holding dot for m = l&7.
        float s_[4];
#pragma unroll
        for (int q = 0; q < 4; ++q) {
            float snd = b0 ? r[2 * q] : r[2 * q + 1];
            float kp  = b0 ? r[2 * q + 1] : r[2 * q];
            s_[q] = kp + __shfl_xor(snd, 1);
        }
        float u_[2];
#pragma unroll
        for (int q = 0; q < 2; ++q) {
            float snd = b1 ? s_[2 * q] : s_[2 * q + 1];
            float kp  = b1 ? s_[2 * q + 1] : s_[2 * q];
            u_[q] = kp + __shfl_xor(snd, 2);
        }
        float d;
        {
            float snd = b2 ? u_[0] : u_[1];
            float kp  = b2 ? u_[1] : u_[0];
            d = kp + __shfl_xor(snd, 4);
        }
        // Cross-octet: full 256-channel dot, replicated across octets.
        d += __shfl_xor(d, 8);
        d += __shfl_xor(d, 16);
        d += __shfl_xor(d, 32);
        const float dsh = fmaxf(d + dsb, 0.f);

        // us-conv for the block's two channels: sum over m (= octet).
        float p0 = usw0 * dsh, p1 = usw1 * dsh;
        p0 += __shfl_xor(p0, 1); p0 += __shfl_xor(p0, 2); p0 += __shfl_xor(p0, 4);
        p1 += __shfl_xor(p1, 1); p1 += __shfl_xor(p1, 2); p1 += __shfl_xor(p1, 4);
        if (l == 0) {
            aL[0][p] = 1.0f / (1.0f + expf(-(usb0 + p0)));
            aL[1][p] = 1.0f / (1.0f + expf(-(usb1 + p1)));
        }
    }
    __syncthreads();

    // ------------------- Phase B: apply + h-swish, 2 planes -----------------
#pragma unroll 1
    for (int ci = 0; ci < 2; ++ci) {
        const size_t plane = (size_t)(n * CC + c0 + ci) * (HH * WW);
        const nvec4* xp = (const nvec4*)(x + plane);
        nvec4* op = (nvec4*)(out + plane);
        const float* ah = aL[ci];
        const float* aw = aL[ci] + HH;
#pragma unroll 4
        for (int i = t; i < HH * (WW / 4); i += 256) {
            const int h = i / (WW / 4);
            const int w4i = i % (WW / 4);
            nvec4 xv = __builtin_nontemporal_load(&xp[i]);
            const float a_h = ah[h];
            nvec4 o;
            o.x = xv.x * (aw[w4i * 4 + 0] * a_h) + xv.x;
            o.y = xv.y * (aw[w4i * 4 + 1] * a_h) + xv.y;
            o.z = xv.z * (aw[w4i * 4 + 2] * a_h) + xv.z;
            o.w = xv.w * (aw[w4i * 4 + 3] * a_h) + xv.w;
            nvec4 rr;
            rr.x = o.x * fminf(fmaxf(o.x + 3.0f, 0.0f), 6.0f) * (1.0f / 6.0f);
            rr.y = o.y * fminf(fmaxf(o.y + 3.0f, 0.0f), 6.0f) * (1.0f / 6.0f);
            rr.z = o.z * fminf(fmaxf(o.z + 3.0f, 0.0f), 6.0f) * (1.0f / 6.0f);
            rr.w = o.w * fminf(fmaxf(o.w + 3.0f, 0.0f), 6.0f) * (1.0f / 6.0f);
            __builtin_nontemporal_store(rr, &op[i]);
        }
    }
}

extern "C" void kernel_launch(void* const* d_in, const int* in_sizes, int n_in,
                              void* d_out, int out_size, void* d_ws, size_t ws_size,
                              hipStream_t stream) {
    const float* x     = (const float*)d_in[0];
    const float* bn1_g = (const float*)d_in[1];
    const float* bn1_b = (const float*)d_in[2];
    const float* bn1_m = (const float*)d_in[3];
    const float* bn1_v = (const float*)d_in[4];
    const float* bn2_g = (const float*)d_in[5];
    const float* bn2_b = (const float*)d_in[6];
    const float* bn2_m = (const float*)d_in[7];
    const float* bn2_v = (const float*)d_in[8];
    const float* ds_w  = (const float*)d_in[9];
    const float* ds_b  = (const float*)d_in[10];
    const float* us_w  = (const float*)d_in[11];
    const float* us_b  = (const float*)d_in[12];
    float* out  = (float*)d_out;
    float* pool = (float*)d_ws;   // 2*N*112*C*4 = 1.75 MB

    pool_bn_kernel<<<NN * CC, 256, 0, stream>>>(x,
        bn1_g, bn1_b, bn1_m, bn1_v, bn2_g, bn2_b, bn2_m, bn2_v, pool);
    att_apply_kernel<<<NN * (CC / 2), 256, 0, stream>>>(x,
        ds_w, ds_b, us_w, us_b, pool, out);
}

// Round 8
// 221.664 us; speedup vs baseline: 3.6316x; 1.1901x over previous
//
#include <hip/hip_runtime.h>
#include <math.h>

#define NN 8
#define CC 256
#define HH 112
#define WW 112
#define MIP 8
#define EPS 1e-5f
#define WOFF (NN * HH * CC)       // w-branch offset in pool buffer

typedef float nvec4 __attribute__((ext_vector_type(4)));

// ---------------------------------------------------------------------------
// K1: dual-axis average pooling with BN folded in (BN is per-channel affine,
// commutes with the mean). One block per (n,c) plane, NT loads (read-once;
// NT loads still allocate into L3 -> x stays L3-hot for K3, proven r4/r7).
// pool layout: h-branch P[(n*HH+h)*CC+c] (bn1 applied);
//              w-branch P[WOFF+(n*WW+w)*CC+c] (bn2 applied).
// ---------------------------------------------------------------------------
__global__ __launch_bounds__(256) void pool_bn_kernel(
    const float* __restrict__ x,
    const float* __restrict__ bn1_g, const float* __restrict__ bn1_b,
    const float* __restrict__ bn1_m, const float* __restrict__ bn1_v,
    const float* __restrict__ bn2_g, const float* __restrict__ bn2_b,
    const float* __restrict__ bn2_m, const float* __restrict__ bn2_v,
    float* __restrict__ pool) {
    __shared__ float rowpart[HH][29];
    __shared__ float4 colpart[8][28];
    const int b = blockIdx.x;                // n*CC + c
    const int n = b / CC;
    const int c = b % CC;
    const int t = threadIdx.x;

    const nvec4* p4 = (const nvec4*)(x + (size_t)b * (HH * WW));

    if (t < 224) {
        const int g = t / 28;                // row group 0..7
        const int j = t % 28;                // float4 column 0..27
        float4 ca = make_float4(0.f, 0.f, 0.f, 0.f);
#pragma unroll
        for (int k = 0; k < 14; ++k) {
            const int r = g + 8 * k;
            nvec4 v = __builtin_nontemporal_load(&p4[r * 28 + j]);
            ca.x += v.x; ca.y += v.y; ca.z += v.z; ca.w += v.w;
            rowpart[r][j] = v.x + v.y + v.z + v.w;
        }
        colpart[g][j] = ca;
    }
    __syncthreads();

    if (t < HH) {
        // row mean (over w) -> h-branch, bn1 folded
        float s = 0.f;
#pragma unroll
        for (int j = 0; j < 28; ++j) s += rowpart[t][j];
        const float sc = bn1_g[c] * rsqrtf(bn1_v[c] + EPS);
        const float sh = bn1_b[c] - bn1_m[c] * sc;
        pool[((size_t)(n * HH + t)) * CC + c] = (s * (1.0f / WW)) * sc + sh;
    } else if (t < 112 + WW) {
        // column mean (over h) -> w-branch, bn2 folded
        const int w = t - 112;
        const float* cp = (const float*)&colpart[0][0];   // [8][112] floats
        float s = 0.f;
#pragma unroll
        for (int g = 0; g < 8; ++g) s += cp[g * 112 + w];
        const float sc = bn2_g[c] * rsqrtf(bn2_v[c] + EPS);
        const float sh = bn2_b[c] - bn2_m[c] * sc;
        pool[(size_t)WOFF + ((size_t)(n * WW + w)) * CC + c] =
            (s * (1.0f / HH)) * sc + sh;
    }
}

// ---------------------------------------------------------------------------
// K2: conv1x1(C->MIP) -> relu -> conv1x1(MIP->C) -> sigmoid (BN already
// applied by K1). grid = (N*112, 2), 256 threads = one channel each, fully
// coalesced; zero redundancy. In-place update of the pooled buffer.
// ---------------------------------------------------------------------------
__global__ __launch_bounds__(256) void att_kernel(
    float* __restrict__ pool,
    const float* __restrict__ ds_w, const float* __restrict__ ds_b,
    const float* __restrict__ us_w, const float* __restrict__ us_b) {
    __shared__ float s[CC];
    __shared__ float dsh[MIP];

    const int branch = blockIdx.y;
    const int c = threadIdx.x;
    const size_t idx =
        (size_t)branch * WOFF + (size_t)blockIdx.x * CC + c;

    s[c] = pool[idx];
    __syncthreads();

    {
        const int grp = c >> 5;
        const int l = c & 31;
        float partial = 0.f;
#pragma unroll
        for (int k = 0; k < CC / 32; ++k) {
            const int cc = l + k * 32;
            partial += ds_w[grp * CC + cc] * s[cc];
        }
#pragma unroll
        for (int off = 16; off > 0; off >>= 1)
            partial += __shfl_down(partial, off, 32);
        if (l == 0) dsh[grp] = fmaxf(partial + ds_b[grp], 0.f);
    }
    __syncthreads();

    float acc = us_b[c];
#pragma unroll
    for (int m = 0; m < MIP; ++m) acc += us_w[c * MIP + m] * dsh[m];
    pool[idx] = 1.0f / (1.0f + expf(-acc));
}

// ---------------------------------------------------------------------------
// K3: apply + h-swish. One block per (n,c) plane: stage 112 ah + 112 aw into
// LDS, then stream x -> out with the SAME 224-thread uniform pattern as K1:
// thread (g,j) walks rows g+8k. No div/mod in the loop; aw[4j..4j+3] are
// loop-invariant registers; body = NT load, 8 VALU, NT store, unroll 14.
// ---------------------------------------------------------------------------
__global__ __launch_bounds__(256) void apply_kernel(
    const float* __restrict__ x,
    const float* __restrict__ att,
    float* __restrict__ out) {
    __shared__ float ah[HH];
    __shared__ float aw[WW];
    const int b = blockIdx.x;              // n*CC + c
    const int n = b / CC;
    const int c = b % CC;
    const int t = threadIdx.x;

    if (t < HH) {
        ah[t] = att[((size_t)(n * HH + t)) * CC + c];
    } else if (t >= 128 && t < 128 + WW) {
        const int w = t - 128;
        aw[w] = att[(size_t)WOFF + ((size_t)(n * WW + w)) * CC + c];
    }
    __syncthreads();

    if (t < 224) {
        const int g = t / 28;              // row group 0..7
        const int j = t % 28;              // float4 column 0..27
        const nvec4* xp = (const nvec4*)(x + (size_t)b * (HH * WW));
        nvec4* op = (nvec4*)(out + (size_t)b * (HH * WW));
        const float a0 = aw[4 * j + 0];
        const float a1 = aw[4 * j + 1];
        const float a2 = aw[4 * j + 2];
        const float a3 = aw[4 * j + 3];
#pragma unroll
        for (int k = 0; k < 14; ++k) {
            const int r = g + 8 * k;
            const int i = r * 28 + j;
            nvec4 xv = __builtin_nontemporal_load(&xp[i]);
            const float a_h = ah[r];
            nvec4 o;
            o.x = xv.x * (a0 * a_h) + xv.x;
            o.y = xv.y * (a1 * a_h) + xv.y;
            o.z = xv.z * (a2 * a_h) + xv.z;
            o.w = xv.w * (a3 * a_h) + xv.w;
            nvec4 r4;
            r4.x = o.x * fminf(fmaxf(o.x + 3.0f, 0.0f), 6.0f) * (1.0f / 6.0f);
            r4.y = o.y * fminf(fmaxf(o.y + 3.0f, 0.0f), 6.0f) * (1.0f / 6.0f);
            r4.z = o.z * fminf(fmaxf(o.z + 3.0f, 0.0f), 6.0f) * (1.0f / 6.0f);
            r4.w = o.w * fminf(fmaxf(o.w + 3.0f, 0.0f), 6.0f) * (1.0f / 6.0f);
            __builtin_nontemporal_store(r4, &op[i]);
        }
    }
}

extern "C" void kernel_launch(void* const* d_in, const int* in_sizes, int n_in,
                              void* d_out, int out_size, void* d_ws, size_t ws_size,
                              hipStream_t stream) {
    const float* x     = (const float*)d_in[0];
    const float* bn1_g = (const float*)d_in[1];
    const float* bn1_b = (const float*)d_in[2];
    const float* bn1_m = (const float*)d_in[3];
    const float* bn1_v = (const float*)d_in[4];
    const float* bn2_g = (const float*)d_in[5];
    const float* bn2_b = (const float*)d_in[6];
    const float* bn2_m = (const float*)d_in[7];
    const float* bn2_v = (const float*)d_in[8];
    const float* ds_w  = (const float*)d_in[9];
    const float* ds_b  = (const float*)d_in[10];
    const float* us_w  = (const float*)d_in[11];
    const float* us_b  = (const float*)d_in[12];
    float* out  = (float*)d_out;
    float* pool = (float*)d_ws;   // 2*N*112*C*4 = 1.75 MB

    pool_bn_kernel<<<NN * CC, 256, 0, stream>>>(x,
        bn1_g, bn1_b, bn1_m, bn1_v, bn2_g, bn2_b, bn2_m, bn2_v, pool);
    att_kernel<<<dim3(NN * HH, 2), 256, 0, stream>>>(pool,
        ds_w, ds_b, us_w, us_b);
    apply_kernel<<<NN * CC, 256, 0, stream>>>(x, pool, out);
}